// Round 13
// baseline (536.356 us; speedup 1.0000x reference)
//
#include <hip/hip_runtime.h>
#include <hip/hip_bf16.h>

// SPRGraphNet: embed -> SAGEConv x2 (mean aggr) -> global mean pool -> linear head
// N=50000, E=800000, G=512, EMB=128, HID=256, NCLS=32. fp32 in/out.
// h tables bf16; all GEMM A-operands in MFMA-fragment-native layout:
//   idx = ((row>>4)*32 + (k>>3))*128 + (row&15)*8 + (k&7)     (32 octets = DIM 256)
// -> every fragment load is 64 lanes x 16B = 1KB contiguous. LDS-free GEMM.

#define EMB   128
#define HID   256
#define NCLS  32
#define DIM   256   // feature width everywhere (2*EMB == HID == 256)

typedef __attribute__((ext_vector_type(8))) short short8v;   // 8 bf16 = 4 VGPR (MFMA A/B frag)
typedef __attribute__((ext_vector_type(4))) float float4v;   // MFMA C/D frag

__device__ __forceinline__ unsigned short f2bf(float f) {    // RNE fp32->bf16 (normals)
    unsigned int u = __float_as_uint(f);
    unsigned int r = u + 0x7FFFu + ((u >> 16) & 1u);
    return (unsigned short)(r >> 16);
}
__device__ __forceinline__ float bf2f(unsigned short s) {
    return __uint_as_float(((unsigned int)s) << 16);
}

// ---------------------------------------------------------------- weight precompute
// Bq[k][o] = k<256 ? wl[o,k] : wr[o,k-256], bf16 hi/lo, fragment-native:
// idx = ((k>>3)*256 + o)*8 + (k&7). Both layers in one launch.
__global__ void build_bq2(const float* __restrict__ w1l, const float* __restrict__ w1r,
                          const float* __restrict__ w2l, const float* __restrict__ w2r,
                          unsigned short* __restrict__ b1hi, unsigned short* __restrict__ b1lo,
                          unsigned short* __restrict__ b2hi, unsigned short* __restrict__ b2lo) {
    int tid = blockIdx.x * 256 + threadIdx.x;   // 2*512*256 threads
    int which = tid >> 17;
    int r = tid & 0x1FFFF;
    int k = r >> 8, o = r & 255;
    const float* wl = which ? w2l : w1l;
    const float* wr = which ? w2r : w1r;
    float v = (k < 256) ? wl[o * 256 + k] : wr[o * 256 + (k - 256)];
    unsigned short h = f2bf(v);
    unsigned short l = f2bf(v - bf2f(h));
    int idx = (((k >> 3) * 256) + o) * 8 + (k & 7);
    (which ? b2hi : b1hi)[idx] = h;
    (which ? b2lo : b1lo)[idx] = l;
}

// h0: row-major bf16 (for gathers) + fragment-native bf16 (for GEMM phase 2)
__global__ void embed_bf16(const int* __restrict__ x,
                           const float* __restrict__ se, const float* __restrict__ ce,
                           unsigned short* __restrict__ hb, unsigned short* __restrict__ hf,
                           int n_nodes) {
    int tid = blockIdx.x * 256 + threadIdx.x;   // n_nodes*32
    if (tid >= n_nodes * 32) return;
    int n = tid >> 5, c = tid & 31;             // c = k-octet index (8 elems)
    const float* src = (c < 16) ? (se + (size_t)x[n * 2] * EMB + c * 8)
                                : (ce + (size_t)x[n * 2 + 1] * EMB + (c - 16) * 8);
    float4 v0 = *(const float4*)src;
    float4 v1 = *(const float4*)(src + 4);
    ushort4 o0 = make_ushort4(f2bf(v0.x), f2bf(v0.y), f2bf(v0.z), f2bf(v0.w));
    ushort4 o1 = make_ushort4(f2bf(v1.x), f2bf(v1.y), f2bf(v1.z), f2bf(v1.w));
    *(ushort4*)(hb + (size_t)tid * 8)     = o0;
    *(ushort4*)(hb + (size_t)tid * 8 + 4) = o1;
    size_t fo = ((size_t)(n >> 4) * 32 + c) * 128 + (n & 15) * 8;
    *(ushort4*)(hf + fo)     = o0;
    *(ushort4*)(hf + fo + 4) = o1;
}

// ---------------------------------------------------------------- CSR build

__global__ void count_deg(const int* __restrict__ dst, int* __restrict__ deg, int E) {
    int e = blockIdx.x * 256 + threadIdx.x;
    if (e < E) atomicAdd(&deg[dst[e]], 1);
}

__global__ void scan_block(const int* __restrict__ deg, int* __restrict__ rowptr,
                           int* __restrict__ bsums, int n) {
    __shared__ int s[256];
    int t = threadIdx.x;
    int i = blockIdx.x * 256 + t;
    int v = (i < n) ? deg[i] : 0;
    s[t] = v; __syncthreads();
    for (int off = 1; off < 256; off <<= 1) {
        int x = (t >= off) ? s[t - off] : 0;
        __syncthreads(); s[t] += x; __syncthreads();
    }
    if (i < n) rowptr[i] = s[t] - v;
    if (t == 255) bsums[blockIdx.x] = s[255];
}

__global__ void scan_sums(int* __restrict__ bsums, int nb, int* __restrict__ rowptr,
                          int n, int E) {
    __shared__ int s[256];
    int t = threadIdx.x;
    int v = (t < nb) ? bsums[t] : 0;
    s[t] = v; __syncthreads();
    for (int off = 1; off < 256; off <<= 1) {
        int x = (t >= off) ? s[t - off] : 0;
        __syncthreads(); s[t] += x; __syncthreads();
    }
    if (t < nb) bsums[t] = s[t] - v;
    if (t == 0) rowptr[n] = E;
}

__global__ void scan_add(int* __restrict__ rowptr, const int* __restrict__ bsums, int n) {
    int i = blockIdx.x * 256 + threadIdx.x;
    if (i < n) rowptr[i] += bsums[i >> 8];
}

__global__ void fill_csr(const int* __restrict__ src, const int* __restrict__ dst,
                         const int* __restrict__ rowptr, int* __restrict__ cursor,
                         int* __restrict__ csr, int E) {
    int e = blockIdx.x * 256 + threadIdx.x;
    if (e >= E) return;
    int d = dst[e];
    int pos = rowptr[d] + atomicAdd(&cursor[d], 1);
    csr[pos] = src[e];
}

// ---------------------------------------------------------------- mean aggregation
// one wave per node; lane l owns k = 4l..4l+3 (8B gather per lane); unroll-4.
// Output: bf16 hi/lo planes in FRAGMENT-NATIVE layout (lane ownership matches:
// k=4l+j -> oct l>>1, sub (l&1)*4 -> strided 8B store, no shuffle needed).
__global__ void aggregate_bf16(const unsigned short* __restrict__ hb,
                               const int* __restrict__ rowptr, const int* __restrict__ csr,
                               unsigned short* __restrict__ ahiF, unsigned short* __restrict__ aloF,
                               int n_nodes) {
    int wid = (blockIdx.x * 256 + threadIdx.x) >> 6;
    int lane = threadIdx.x & 63;
    if (wid >= n_nodes) return;
    int beg = rowptr[wid], end = rowptr[wid + 1];
    float a0 = 0.f, a1 = 0.f, a2 = 0.f, a3 = 0.f;
    int k = beg;
    for (; k + 3 < end; k += 4) {
        int s0 = csr[k], s1 = csr[k + 1], s2 = csr[k + 2], s3 = csr[k + 3];
        ushort4 u0 = *(const ushort4*)(hb + (size_t)s0 * DIM + lane * 4);
        ushort4 u1 = *(const ushort4*)(hb + (size_t)s1 * DIM + lane * 4);
        ushort4 u2 = *(const ushort4*)(hb + (size_t)s2 * DIM + lane * 4);
        ushort4 u3 = *(const ushort4*)(hb + (size_t)s3 * DIM + lane * 4);
        a0 += bf2f(u0.x) + bf2f(u1.x) + bf2f(u2.x) + bf2f(u3.x);
        a1 += bf2f(u0.y) + bf2f(u1.y) + bf2f(u2.y) + bf2f(u3.y);
        a2 += bf2f(u0.z) + bf2f(u1.z) + bf2f(u2.z) + bf2f(u3.z);
        a3 += bf2f(u0.w) + bf2f(u1.w) + bf2f(u2.w) + bf2f(u3.w);
    }
    for (; k < end; ++k) {
        ushort4 u = *(const ushort4*)(hb + (size_t)csr[k] * DIM + lane * 4);
        a0 += bf2f(u.x); a1 += bf2f(u.y); a2 += bf2f(u.z); a3 += bf2f(u.w);
    }
    int d = end - beg;
    float inv = 1.0f / (float)(d > 1 ? d : 1);
    float v[4] = {a0 * inv, a1 * inv, a2 * inv, a3 * inv};
    unsigned short hs[4], ls[4];
#pragma unroll
    for (int i = 0; i < 4; ++i) {
        hs[i] = f2bf(v[i]);
        ls[i] = f2bf(v[i] - bf2f(hs[i]));
    }
    size_t base = ((size_t)(wid >> 4) * 32 + (lane >> 1)) * 128 + (wid & 15) * 8 + (lane & 1) * 4;
    *(ushort4*)(ahiF + base) = make_ushort4(hs[0], hs[1], hs[2], hs[3]);
    *(ushort4*)(aloF + base) = make_ushort4(ls[0], ls[1], ls[2], ls[3]);
}

// ---------------------------------------------------------------- MFMA SAGE GEMM
// Hout[m,n] = relu( sum_k Agg[m,k]*Wl[n,k] + Hin[m,k]*Wr[n,k] + bias[n] )
// LDS-free, barrier-free; ALL operands fragment-native -> 1KB-contiguous loads.
// Block 128x64 (4 waves as 2Mx2N), wave tile 64x32. Grid (256/64, M/128).
// Agg: hi/lo (3 MFMA); Hin: bf16 exact (2 MFMA).
__global__ void __launch_bounds__(256, 3)
gemm_mfma(const unsigned short* __restrict__ Ahi, const unsigned short* __restrict__ Alo,
          const unsigned short* __restrict__ Hf,
          const unsigned short* __restrict__ Bhi, const unsigned short* __restrict__ Blo,
          const float* __restrict__ bias,
          float* __restrict__ Houtf, unsigned short* __restrict__ Houtb,
          unsigned short* __restrict__ Hfrag, int M) {
    const int t = threadIdx.x;
    const int w = t >> 6, lane = t & 63;
    const int lrow = lane & 15, koct = lane >> 4;
    const int wm = w >> 1, wn = w & 1;
    const int rb = blockIdx.y * 128 + wm * 64;    // wave row base (mult of 16)
    const int cb = blockIdx.x * 64 + wn * 32;     // wave col base
    const int mbmax = (M >> 4) - 1;

    size_t abase[4];                              // frag-native row-block bases
#pragma unroll
    for (int mt = 0; mt < 4; ++mt) {
        int mb = (rb >> 4) + mt;
        if (mb > mbmax) mb = mbmax;               // tail clamp; epilogue masks
        abase[mt] = (size_t)mb * 32 * 128 + lrow * 8;
    }
    const int col0 = cb + lrow;

    float4v acc[4][2];
#pragma unroll
    for (int i = 0; i < 4; ++i)
#pragma unroll
        for (int j = 0; j < 2; ++j) acc[i][j] = (float4v){0.f, 0.f, 0.f, 0.f};

    // ---- phase 1: K = 0..255 (Agg hi/lo, 3 MFMAs per frag pair) ----
#pragma unroll 2
    for (int kt = 0; kt < 8; ++kt) {
        const size_t kof = (size_t)(kt * 4 + koct) * 128;
        const int kg = kt * 4 + koct;
        short8v ah[4], al[4], bh[2], bl[2];
#pragma unroll
        for (int mt = 0; mt < 4; ++mt) {
            ah[mt] = *(const short8v*)(Ahi + abase[mt] + kof);
            al[mt] = *(const short8v*)(Alo + abase[mt] + kof);
        }
#pragma unroll
        for (int nt = 0; nt < 2; ++nt) {
            size_t bofs = ((size_t)kg * 256 + col0 + nt * 16) * 8;
            bh[nt] = *(const short8v*)(Bhi + bofs);
            bl[nt] = *(const short8v*)(Blo + bofs);
        }
#pragma unroll
        for (int mt = 0; mt < 4; ++mt)
#pragma unroll
            for (int nt = 0; nt < 2; ++nt) {
                acc[mt][nt] = __builtin_amdgcn_mfma_f32_16x16x32_bf16(ah[mt], bh[nt], acc[mt][nt], 0, 0, 0);
                acc[mt][nt] = __builtin_amdgcn_mfma_f32_16x16x32_bf16(ah[mt], bl[nt], acc[mt][nt], 0, 0, 0);
                acc[mt][nt] = __builtin_amdgcn_mfma_f32_16x16x32_bf16(al[mt], bh[nt], acc[mt][nt], 0, 0, 0);
            }
    }

    // ---- phase 2: K = 256..511 (Hin bf16 exact, 2 MFMAs) ----
#pragma unroll 2
    for (int kt = 0; kt < 8; ++kt) {
        const size_t kof = (size_t)(kt * 4 + koct) * 128;
        const int kg = (kt + 8) * 4 + koct;
        short8v ah[4], bh[2], bl[2];
#pragma unroll
        for (int mt = 0; mt < 4; ++mt)
            ah[mt] = *(const short8v*)(Hf + abase[mt] + kof);
#pragma unroll
        for (int nt = 0; nt < 2; ++nt) {
            size_t bofs = ((size_t)kg * 256 + col0 + nt * 16) * 8;
            bh[nt] = *(const short8v*)(Bhi + bofs);
            bl[nt] = *(const short8v*)(Blo + bofs);
        }
#pragma unroll
        for (int mt = 0; mt < 4; ++mt)
#pragma unroll
            for (int nt = 0; nt < 2; ++nt) {
                acc[mt][nt] = __builtin_amdgcn_mfma_f32_16x16x32_bf16(ah[mt], bh[nt], acc[mt][nt], 0, 0, 0);
                acc[mt][nt] = __builtin_amdgcn_mfma_f32_16x16x32_bf16(ah[mt], bl[nt], acc[mt][nt], 0, 0, 0);
            }
    }

    // ---- epilogue: bias + relu; C/D map col=lane&15, row=(lane>>4)*4+reg ----
    float bv[2];
#pragma unroll
    for (int nt = 0; nt < 2; ++nt) bv[nt] = bias[cb + nt * 16 + lrow];

#pragma unroll
    for (int mt = 0; mt < 4; ++mt) {
#pragma unroll
        for (int r = 0; r < 4; ++r) {
            int grow = rb + mt * 16 + koct * 4 + r;
            if (grow >= M) continue;
            size_t fbase = ((size_t)(grow >> 4) * 32) * 128 + (grow & 15) * 8;
#pragma unroll
            for (int nt = 0; nt < 2; ++nt) {
                float vv = fmaxf(acc[mt][nt][r] + bv[nt], 0.f);
                int col = cb + nt * 16 + lrow;
                if (Houtf) Houtf[(size_t)grow * DIM + col] = vv;
                if (Houtb) Houtb[(size_t)grow * DIM + col] = f2bf(vv);
                if (Hfrag) Hfrag[fbase + (size_t)(col >> 3) * 128 + (col & 7)] = f2bf(vv);
            }
        }
    }
}

// ---------------------------------------------------------------- pooling + head

__global__ void pool_kernel(const float* __restrict__ h, const int* __restrict__ batch,
                            float* __restrict__ hg, int n_nodes) {
    int g = blockIdx.x;
    int t = threadIdx.x;
    int lo = 0, hi = n_nodes;
    while (lo < hi) { int mid = (lo + hi) >> 1; if (batch[mid] < g) lo = mid + 1; else hi = mid; }
    int start = lo;
    hi = n_nodes;
    while (lo < hi) { int mid = (lo + hi) >> 1; if (batch[mid] < g + 1) lo = mid + 1; else hi = mid; }
    int end = lo;
    float acc = 0.f;
    for (int n = start; n < end; ++n) acc += h[(size_t)n * DIM + t];
    int c = end - start;
    hg[g * DIM + t] = acc / (float)(c > 1 ? c : 1);
}

__global__ void head_kernel(const float* __restrict__ hg, const float* __restrict__ wc,
                            const float* __restrict__ bc, float* __restrict__ out, int total) {
    int tid = blockIdx.x * 256 + threadIdx.x;
    if (tid >= total) return;
    int g = tid >> 5, c = tid & 31;
    const float* hr = hg + (size_t)g * DIM;
    const float* wr = wc + (size_t)c * DIM;
    float acc = bc[c];
    for (int k = 0; k < DIM; ++k) acc = fmaf(hr[k], wr[k], acc);
    out[tid] = acc;
}

// ---------------------------------------------------------------- launch

extern "C" void kernel_launch(void* const* d_in, const int* in_sizes, int n_in,
                              void* d_out, int out_size, void* d_ws, size_t ws_size,
                              hipStream_t stream) {
    const int* x      = (const int*)d_in[0];
    const int* ei     = (const int*)d_in[1];
    const int* batch  = (const int*)d_in[2];
    const float* se   = (const float*)d_in[3];
    const float* ce   = (const float*)d_in[4];
    const float* w1l  = (const float*)d_in[5];
    const float* b1l  = (const float*)d_in[6];
    const float* w1r  = (const float*)d_in[7];
    const float* w2l  = (const float*)d_in[8];
    const float* b2l  = (const float*)d_in[9];
    const float* w2r  = (const float*)d_in[10];
    const float* wc   = (const float*)d_in[11];
    const float* bc   = (const float*)d_in[12];
    float* out = (float*)d_out;

    const int N = in_sizes[0] / 2;
    const int E = in_sizes[1] / 2;
    const int G = out_size / NCLS;
    const int* src = ei;
    const int* dst = ei + E;

    // workspace carve-up
    float* h2 = (float*)d_ws;                               // N*256 f32
    unsigned short* agghiF = (unsigned short*)(h2 + (size_t)N * DIM); // frag-native planes
    unsigned short* aggloF = agghiF + (size_t)N * DIM;
    unsigned short* h0b    = aggloF + (size_t)N * DIM;      // row-major (gather)
    unsigned short* h0f    = h0b + (size_t)N * DIM;         // frag-native
    unsigned short* h1b    = h0f + (size_t)N * DIM;         // row-major (gather)
    unsigned short* h1f    = h1b + (size_t)N * DIM;         // frag-native
    unsigned short* B1hi   = h1f + (size_t)N * DIM;         // 512*256 each
    unsigned short* B1lo   = B1hi + 131072;
    unsigned short* B2hi   = B1lo + 131072;
    unsigned short* B2lo   = B2hi + 131072;
    float* hg  = (float*)(B2lo + 131072);                   // G*256
    int* deg    = (int*)(hg + (size_t)G * DIM);             // N
    int* rowptr = deg + N;                                  // N+1
    int* cursor = rowptr + (N + 1);                         // N
    int* csr    = cursor + N;                               // E
    int* bsums  = csr + E;                                  // <=256

    hipMemsetAsync(deg, 0, (size_t)(3 * N + 1) * sizeof(int), stream);

    embed_bf16<<<(N * 32 + 255) / 256, 256, 0, stream>>>(x, se, ce, h0b, h0f, N);

    int eblocks = (E + 255) / 256;
    count_deg<<<eblocks, 256, 0, stream>>>(dst, deg, E);
    int sblocks = (N + 255) / 256;
    scan_block<<<sblocks, 256, 0, stream>>>(deg, rowptr, bsums, N);
    scan_sums<<<1, 256, 0, stream>>>(bsums, sblocks, rowptr, N, E);
    scan_add<<<sblocks, 256, 0, stream>>>(rowptr, bsums, N);
    fill_csr<<<eblocks, 256, 0, stream>>>(src, dst, rowptr, cursor, csr, E);

    build_bq2<<<1024, 256, 0, stream>>>(w1l, w1r, w2l, w2r, B1hi, B1lo, B2hi, B2lo);

    dim3 ggrid(256 / 64, (N + 127) / 128);                  // (4, 391)
    int ablocks = (N * 64 + 255) / 256;

    // layer 1: h0b -> agg(frag hi/lo) -> h1b (row-major) + h1f (frag-native)
    aggregate_bf16<<<ablocks, 256, 0, stream>>>(h0b, rowptr, csr, agghiF, aggloF, N);
    gemm_mfma<<<ggrid, 256, 0, stream>>>(agghiF, aggloF, h0f, B1hi, B1lo, b1l,
                                         nullptr, h1b, h1f, N);

    // layer 2: h1b -> agg(frag hi/lo) -> h2 (fp32 row-major for pooling)
    aggregate_bf16<<<ablocks, 256, 0, stream>>>(h1b, rowptr, csr, agghiF, aggloF, N);
    gemm_mfma<<<ggrid, 256, 0, stream>>>(agghiF, aggloF, h1f, B2hi, B2lo, b2l,
                                         h2, nullptr, nullptr, N);

    pool_kernel<<<G, 256, 0, stream>>>(h2, batch, hg, N);
    head_kernel<<<(G * NCLS + 255) / 256, 256, 0, stream>>>(hg, wc, bc, out, G * NCLS);
}

// Round 15
// 525.124 us; speedup vs baseline: 1.0214x; 1.0214x over previous
//
#include <hip/hip_runtime.h>
#include <hip/hip_bf16.h>

// SPRGraphNet: embed -> SAGEConv x2 (mean aggr) -> global mean pool -> linear head
// N=50000, E=800000, G=512, EMB=128, HID=256, NCLS=32. fp32 in/out.
// h tables bf16; GEMM A-operands in MFMA-fragment-native layout:
//   idx = ((row>>4)*32 + (k>>3))*128 + (row&15)*8 + (k&7)     (32 octets = DIM 256)
// GEMM v2: BM=64 x BN=256 (A read ONCE per block - fixes R13's 4x replication),
// 4 waves each 64x64 cols, LDS-free, barrier-free, coalesced frag loads.

#define EMB   128
#define HID   256
#define NCLS  32
#define DIM   256   // feature width everywhere (2*EMB == HID == 256)

typedef __attribute__((ext_vector_type(8))) short short8v;   // 8 bf16 = 4 VGPR (MFMA A/B frag)
typedef __attribute__((ext_vector_type(4))) float float4v;   // MFMA C/D frag

__device__ __forceinline__ unsigned short f2bf(float f) {    // RNE fp32->bf16 (normals)
    unsigned int u = __float_as_uint(f);
    unsigned int r = u + 0x7FFFu + ((u >> 16) & 1u);
    return (unsigned short)(r >> 16);
}
__device__ __forceinline__ float bf2f(unsigned short s) {
    return __uint_as_float(((unsigned int)s) << 16);
}

// ---------------------------------------------------------------- weight precompute
// Bq[k][o] = k<256 ? wl[o,k] : wr[o,k-256], bf16 hi/lo, fragment-native:
// idx = ((k>>3)*256 + o)*8 + (k&7). Both layers in one launch.
__global__ void build_bq2(const float* __restrict__ w1l, const float* __restrict__ w1r,
                          const float* __restrict__ w2l, const float* __restrict__ w2r,
                          unsigned short* __restrict__ b1hi, unsigned short* __restrict__ b1lo,
                          unsigned short* __restrict__ b2hi, unsigned short* __restrict__ b2lo) {
    int tid = blockIdx.x * 256 + threadIdx.x;   // 2*512*256 threads
    int which = tid >> 17;
    int r = tid & 0x1FFFF;
    int k = r >> 8, o = r & 255;
    const float* wl = which ? w2l : w1l;
    const float* wr = which ? w2r : w1r;
    float v = (k < 256) ? wl[o * 256 + k] : wr[o * 256 + (k - 256)];
    unsigned short h = f2bf(v);
    unsigned short l = f2bf(v - bf2f(h));
    int idx = (((k >> 3) * 256) + o) * 8 + (k & 7);
    (which ? b2hi : b1hi)[idx] = h;
    (which ? b2lo : b1lo)[idx] = l;
}

// h0: row-major bf16 (for gathers) + fragment-native bf16 (for GEMM phase 2)
__global__ void embed_bf16(const int* __restrict__ x,
                           const float* __restrict__ se, const float* __restrict__ ce,
                           unsigned short* __restrict__ hb, unsigned short* __restrict__ hf,
                           int n_nodes) {
    int tid = blockIdx.x * 256 + threadIdx.x;   // n_nodes*32
    if (tid >= n_nodes * 32) return;
    int n = tid >> 5, c = tid & 31;             // c = k-octet index (8 elems)
    const float* src = (c < 16) ? (se + (size_t)x[n * 2] * EMB + c * 8)
                                : (ce + (size_t)x[n * 2 + 1] * EMB + (c - 16) * 8);
    float4 v0 = *(const float4*)src;
    float4 v1 = *(const float4*)(src + 4);
    ushort4 o0 = make_ushort4(f2bf(v0.x), f2bf(v0.y), f2bf(v0.z), f2bf(v0.w));
    ushort4 o1 = make_ushort4(f2bf(v1.x), f2bf(v1.y), f2bf(v1.z), f2bf(v1.w));
    *(ushort4*)(hb + (size_t)tid * 8)     = o0;
    *(ushort4*)(hb + (size_t)tid * 8 + 4) = o1;
    size_t fo = ((size_t)(n >> 4) * 32 + c) * 128 + (n & 15) * 8;
    *(ushort4*)(hf + fo)     = o0;
    *(ushort4*)(hf + fo + 4) = o1;
}

// ---------------------------------------------------------------- CSR build

__global__ void count_deg(const int* __restrict__ dst, int* __restrict__ deg, int E) {
    int e = blockIdx.x * 256 + threadIdx.x;
    if (e < E) atomicAdd(&deg[dst[e]], 1);
}

__global__ void scan_block(const int* __restrict__ deg, int* __restrict__ rowptr,
                           int* __restrict__ bsums, int n) {
    __shared__ int s[256];
    int t = threadIdx.x;
    int i = blockIdx.x * 256 + t;
    int v = (i < n) ? deg[i] : 0;
    s[t] = v; __syncthreads();
    for (int off = 1; off < 256; off <<= 1) {
        int x = (t >= off) ? s[t - off] : 0;
        __syncthreads(); s[t] += x; __syncthreads();
    }
    if (i < n) rowptr[i] = s[t] - v;
    if (t == 255) bsums[blockIdx.x] = s[255];
}

__global__ void scan_sums(int* __restrict__ bsums, int nb, int* __restrict__ rowptr,
                          int n, int E) {
    __shared__ int s[256];
    int t = threadIdx.x;
    int v = (t < nb) ? bsums[t] : 0;
    s[t] = v; __syncthreads();
    for (int off = 1; off < 256; off <<= 1) {
        int x = (t >= off) ? s[t - off] : 0;
        __syncthreads(); s[t] += x; __syncthreads();
    }
    if (t < nb) bsums[t] = s[t] - v;
    if (t == 0) rowptr[n] = E;
}

__global__ void scan_add(int* __restrict__ rowptr, const int* __restrict__ bsums, int n) {
    int i = blockIdx.x * 256 + threadIdx.x;
    if (i < n) rowptr[i] += bsums[i >> 8];
}

__global__ void fill_csr(const int* __restrict__ src, const int* __restrict__ dst,
                         const int* __restrict__ rowptr, int* __restrict__ cursor,
                         int* __restrict__ csr, int E) {
    int e = blockIdx.x * 256 + threadIdx.x;
    if (e >= E) return;
    int d = dst[e];
    int pos = rowptr[d] + atomicAdd(&cursor[d], 1);
    csr[pos] = src[e];
}

// ---------------------------------------------------------------- mean aggregation
// one wave per node; lane l owns k = 4l..4l+3 (8B gather per lane); unroll-4.
// Output: bf16 hi/lo planes in FRAGMENT-NATIVE layout.
__global__ void aggregate_bf16(const unsigned short* __restrict__ hb,
                               const int* __restrict__ rowptr, const int* __restrict__ csr,
                               unsigned short* __restrict__ ahiF, unsigned short* __restrict__ aloF,
                               int n_nodes) {
    int wid = (blockIdx.x * 256 + threadIdx.x) >> 6;
    int lane = threadIdx.x & 63;
    if (wid >= n_nodes) return;
    int beg = rowptr[wid], end = rowptr[wid + 1];
    float a0 = 0.f, a1 = 0.f, a2 = 0.f, a3 = 0.f;
    int k = beg;
    for (; k + 3 < end; k += 4) {
        int s0 = csr[k], s1 = csr[k + 1], s2 = csr[k + 2], s3 = csr[k + 3];
        ushort4 u0 = *(const ushort4*)(hb + (size_t)s0 * DIM + lane * 4);
        ushort4 u1 = *(const ushort4*)(hb + (size_t)s1 * DIM + lane * 4);
        ushort4 u2 = *(const ushort4*)(hb + (size_t)s2 * DIM + lane * 4);
        ushort4 u3 = *(const ushort4*)(hb + (size_t)s3 * DIM + lane * 4);
        a0 += bf2f(u0.x) + bf2f(u1.x) + bf2f(u2.x) + bf2f(u3.x);
        a1 += bf2f(u0.y) + bf2f(u1.y) + bf2f(u2.y) + bf2f(u3.y);
        a2 += bf2f(u0.z) + bf2f(u1.z) + bf2f(u2.z) + bf2f(u3.z);
        a3 += bf2f(u0.w) + bf2f(u1.w) + bf2f(u2.w) + bf2f(u3.w);
    }
    for (; k < end; ++k) {
        ushort4 u = *(const ushort4*)(hb + (size_t)csr[k] * DIM + lane * 4);
        a0 += bf2f(u.x); a1 += bf2f(u.y); a2 += bf2f(u.z); a3 += bf2f(u.w);
    }
    int d = end - beg;
    float inv = 1.0f / (float)(d > 1 ? d : 1);
    float v[4] = {a0 * inv, a1 * inv, a2 * inv, a3 * inv};
    unsigned short hs[4], ls[4];
#pragma unroll
    for (int i = 0; i < 4; ++i) {
        hs[i] = f2bf(v[i]);
        ls[i] = f2bf(v[i] - bf2f(hs[i]));
    }
    size_t base = ((size_t)(wid >> 4) * 32 + (lane >> 1)) * 128 + (wid & 15) * 8 + (lane & 1) * 4;
    *(ushort4*)(ahiF + base) = make_ushort4(hs[0], hs[1], hs[2], hs[3]);
    *(ushort4*)(aloF + base) = make_ushort4(ls[0], ls[1], ls[2], ls[3]);
}

// ---------------------------------------------------------------- MFMA SAGE GEMM v2
// Hout[m,n] = relu( sum_k Agg[m,k]*Wl[n,k] + Hin[m,k]*Wr[n,k] + bias[n] )
// BM=64, BN=256 (A read ONCE per block), 4 waves each 64 rows x 64 cols.
// LDS-free, barrier-free; frag-native A (1KB-contiguous, shared by all 4 waves
// -> L1 reuse) + frag-native B (L2-resident). Agg: hi/lo 3 MFMA; Hin: 2 MFMA.
__global__ void __launch_bounds__(256, 3)
gemm_mfma(const unsigned short* __restrict__ Ahi, const unsigned short* __restrict__ Alo,
          const unsigned short* __restrict__ Hf,
          const unsigned short* __restrict__ Bhi, const unsigned short* __restrict__ Blo,
          const float* __restrict__ bias,
          float* __restrict__ Houtf, unsigned short* __restrict__ Houtb,
          unsigned short* __restrict__ Hfrag, int M) {
    const int t = threadIdx.x;
    const int w = t >> 6, lane = t & 63;
    const int lrow = lane & 15, koct = lane >> 4;
    const int m0 = blockIdx.x * 64;               // block rows (shared by all waves)
    const int nw = w * 64;                        // wave col base
    const int mbmax = (M >> 4) - 1;

    size_t abase[4];                              // frag-native row-block bases
#pragma unroll
    for (int mt = 0; mt < 4; ++mt) {
        int mb = (m0 >> 4) + mt;
        if (mb > mbmax) mb = mbmax;               // tail clamp; epilogue masks
        abase[mt] = (size_t)mb * 32 * 128 + lrow * 8;
    }
    const int col0 = nw + lrow;

    float4v acc[4][4];
#pragma unroll
    for (int i = 0; i < 4; ++i)
#pragma unroll
        for (int j = 0; j < 4; ++j) acc[i][j] = (float4v){0.f, 0.f, 0.f, 0.f};

    // ---- phase 1: K = 0..255 (Agg hi/lo, 3 MFMAs per frag pair) ----
#pragma unroll 2
    for (int kt = 0; kt < 8; ++kt) {
        const size_t kof = (size_t)(kt * 4 + koct) * 128;
        const int kg = kt * 4 + koct;
        short8v ah[4], al[4], bh[4], bl[4];
#pragma unroll
        for (int mt = 0; mt < 4; ++mt) {
            ah[mt] = *(const short8v*)(Ahi + abase[mt] + kof);
            al[mt] = *(const short8v*)(Alo + abase[mt] + kof);
        }
#pragma unroll
        for (int nt = 0; nt < 4; ++nt) {
            size_t bofs = ((size_t)kg * 256 + col0 + nt * 16) * 8;
            bh[nt] = *(const short8v*)(Bhi + bofs);
            bl[nt] = *(const short8v*)(Blo + bofs);
        }
#pragma unroll
        for (int mt = 0; mt < 4; ++mt)
#pragma unroll
            for (int nt = 0; nt < 4; ++nt) {
                acc[mt][nt] = __builtin_amdgcn_mfma_f32_16x16x32_bf16(ah[mt], bh[nt], acc[mt][nt], 0, 0, 0);
                acc[mt][nt] = __builtin_amdgcn_mfma_f32_16x16x32_bf16(ah[mt], bl[nt], acc[mt][nt], 0, 0, 0);
                acc[mt][nt] = __builtin_amdgcn_mfma_f32_16x16x32_bf16(al[mt], bh[nt], acc[mt][nt], 0, 0, 0);
            }
    }

    // ---- phase 2: K = 256..511 (Hin bf16 exact, 2 MFMAs) ----
#pragma unroll 2
    for (int kt = 0; kt < 8; ++kt) {
        const size_t kof = (size_t)(kt * 4 + koct) * 128;
        const int kg = (kt + 8) * 4 + koct;
        short8v ah[4], bh[4], bl[4];
#pragma unroll
        for (int mt = 0; mt < 4; ++mt)
            ah[mt] = *(const short8v*)(Hf + abase[mt] + kof);
#pragma unroll
        for (int nt = 0; nt < 4; ++nt) {
            size_t bofs = ((size_t)kg * 256 + col0 + nt * 16) * 8;
            bh[nt] = *(const short8v*)(Bhi + bofs);
            bl[nt] = *(const short8v*)(Blo + bofs);
        }
#pragma unroll
        for (int mt = 0; mt < 4; ++mt)
#pragma unroll
            for (int nt = 0; nt < 4; ++nt) {
                acc[mt][nt] = __builtin_amdgcn_mfma_f32_16x16x32_bf16(ah[mt], bh[nt], acc[mt][nt], 0, 0, 0);
                acc[mt][nt] = __builtin_amdgcn_mfma_f32_16x16x32_bf16(ah[mt], bl[nt], acc[mt][nt], 0, 0, 0);
            }
    }

    // ---- epilogue: bias + relu; C/D map col=lane&15, row=(lane>>4)*4+reg ----
    float bv[4];
#pragma unroll
    for (int nt = 0; nt < 4; ++nt) bv[nt] = bias[nw + nt * 16 + lrow];

#pragma unroll
    for (int mt = 0; mt < 4; ++mt) {
#pragma unroll
        for (int r = 0; r < 4; ++r) {
            int grow = m0 + mt * 16 + koct * 4 + r;
            if (grow >= M) continue;
            size_t fbase = ((size_t)(grow >> 4) * 32) * 128 + (grow & 15) * 8;
#pragma unroll
            for (int nt = 0; nt < 4; ++nt) {
                float vv = fmaxf(acc[mt][nt][r] + bv[nt], 0.f);
                int col = nw + nt * 16 + lrow;
                if (Houtf) Houtf[(size_t)grow * DIM + col] = vv;
                if (Houtb) Houtb[(size_t)grow * DIM + col] = f2bf(vv);
                if (Hfrag) Hfrag[fbase + (size_t)(col >> 3) * 128 + (col & 7)] = f2bf(vv);
            }
        }
    }
}

// ---------------------------------------------------------------- pooling + head

__global__ void pool_kernel(const float* __restrict__ h, const int* __restrict__ batch,
                            float* __restrict__ hg, int n_nodes) {
    int g = blockIdx.x;
    int t = threadIdx.x;
    int lo = 0, hi = n_nodes;
    while (lo < hi) { int mid = (lo + hi) >> 1; if (batch[mid] < g) lo = mid + 1; else hi = mid; }
    int start = lo;
    hi = n_nodes;
    while (lo < hi) { int mid = (lo + hi) >> 1; if (batch[mid] < g + 1) lo = mid + 1; else hi = mid; }
    int end = lo;
    float acc = 0.f;
    for (int n = start; n < end; ++n) acc += h[(size_t)n * DIM + t];
    int c = end - start;
    hg[g * DIM + t] = acc / (float)(c > 1 ? c : 1);
}

__global__ void head_kernel(const float* __restrict__ hg, const float* __restrict__ wc,
                            const float* __restrict__ bc, float* __restrict__ out, int total) {
    int tid = blockIdx.x * 256 + threadIdx.x;
    if (tid >= total) return;
    int g = tid >> 5, c = tid & 31;
    const float* hr = hg + (size_t)g * DIM;
    const float* wr = wc + (size_t)c * DIM;
    float acc = bc[c];
    for (int k = 0; k < DIM; ++k) acc = fmaf(hr[k], wr[k], acc);
    out[tid] = acc;
}

// ---------------------------------------------------------------- launch

extern "C" void kernel_launch(void* const* d_in, const int* in_sizes, int n_in,
                              void* d_out, int out_size, void* d_ws, size_t ws_size,
                              hipStream_t stream) {
    const int* x      = (const int*)d_in[0];
    const int* ei     = (const int*)d_in[1];
    const int* batch  = (const int*)d_in[2];
    const float* se   = (const float*)d_in[3];
    const float* ce   = (const float*)d_in[4];
    const float* w1l  = (const float*)d_in[5];
    const float* b1l  = (const float*)d_in[6];
    const float* w1r  = (const float*)d_in[7];
    const float* w2l  = (const float*)d_in[8];
    const float* b2l  = (const float*)d_in[9];
    const float* w2r  = (const float*)d_in[10];
    const float* wc   = (const float*)d_in[11];
    const float* bc   = (const float*)d_in[12];
    float* out = (float*)d_out;

    const int N = in_sizes[0] / 2;
    const int E = in_sizes[1] / 2;
    const int G = out_size / NCLS;
    const int* src = ei;
    const int* dst = ei + E;

    // workspace carve-up
    float* h2 = (float*)d_ws;                               // N*256 f32
    unsigned short* agghiF = (unsigned short*)(h2 + (size_t)N * DIM); // frag-native planes
    unsigned short* aggloF = agghiF + (size_t)N * DIM;
    unsigned short* h0b    = aggloF + (size_t)N * DIM;      // row-major (gather)
    unsigned short* h0f    = h0b + (size_t)N * DIM;         // frag-native
    unsigned short* h1b    = h0f + (size_t)N * DIM;         // row-major (gather)
    unsigned short* h1f    = h1b + (size_t)N * DIM;         // frag-native
    unsigned short* B1hi   = h1f + (size_t)N * DIM;         // 512*256 each
    unsigned short* B1lo   = B1hi + 131072;
    unsigned short* B2hi   = B1lo + 131072;
    unsigned short* B2lo   = B2hi + 131072;
    float* hg  = (float*)(B2lo + 131072);                   // G*256
    int* deg    = (int*)(hg + (size_t)G * DIM);             // N
    int* rowptr = deg + N;                                  // N+1
    int* cursor = rowptr + (N + 1);                         // N
    int* csr    = cursor + N;                               // E
    int* bsums  = csr + E;                                  // <=256

    hipMemsetAsync(deg, 0, (size_t)(3 * N + 1) * sizeof(int), stream);

    embed_bf16<<<(N * 32 + 255) / 256, 256, 0, stream>>>(x, se, ce, h0b, h0f, N);

    int eblocks = (E + 255) / 256;
    count_deg<<<eblocks, 256, 0, stream>>>(dst, deg, E);
    int sblocks = (N + 255) / 256;
    scan_block<<<sblocks, 256, 0, stream>>>(deg, rowptr, bsums, N);
    scan_sums<<<1, 256, 0, stream>>>(bsums, sblocks, rowptr, N, E);
    scan_add<<<sblocks, 256, 0, stream>>>(rowptr, bsums, N);
    fill_csr<<<eblocks, 256, 0, stream>>>(src, dst, rowptr, cursor, csr, E);

    build_bq2<<<1024, 256, 0, stream>>>(w1l, w1r, w2l, w2r, B1hi, B1lo, B2hi, B2lo);

    int gblocks = (N + 63) / 64;                            // 782 (BM=64, BN=256)
    int ablocks = (N * 64 + 255) / 256;

    // layer 1: h0b -> agg(frag hi/lo) -> h1b (row-major) + h1f (frag-native)
    aggregate_bf16<<<ablocks, 256, 0, stream>>>(h0b, rowptr, csr, agghiF, aggloF, N);
    gemm_mfma<<<gblocks, 256, 0, stream>>>(agghiF, aggloF, h0f, B1hi, B1lo, b1l,
                                           nullptr, h1b, h1f, N);

    // layer 2: h1b -> agg(frag hi/lo) -> h2 (fp32 row-major for pooling)
    aggregate_bf16<<<ablocks, 256, 0, stream>>>(h1b, rowptr, csr, agghiF, aggloF, N);
    gemm_mfma<<<gblocks, 256, 0, stream>>>(agghiF, aggloF, h1f, B2hi, B2lo, b2l,
                                           h2, nullptr, nullptr, N);

    pool_kernel<<<G, 256, 0, stream>>>(h2, batch, hg, N);
    head_kernel<<<(G * NCLS + 255) / 256, 256, 0, stream>>>(hg, wc, bc, out, G * NCLS);
}

// Round 16
// 472.584 us; speedup vs baseline: 1.1349x; 1.1112x over previous
//
#include <hip/hip_runtime.h>
#include <hip/hip_bf16.h>

// SPRGraphNet: embed -> SAGEConv x2 (mean aggr) -> global mean pool -> linear head
// N=50000, E=800000, G=512, EMB=128, HID=256, NCLS=32. fp32 in/out.
// h tables bf16; GEMM A-operands in MFMA-fragment-native layout:
//   idx = ((row>>4)*32 + (k>>3))*128 + (row&15)*8 + (k&7)     (32 octets = DIM 256)
// GEMM v3: BM=64 x BN=256 read-once + block's Ahi/Alo staged to LDS (64KB, once,
// one barrier) -> K-loop reads A via ds_read_b128 (~120cy) instead of global.
// 8 waves (512 thr), wave tile 64x32, 2 blocks/CU -> 4 waves/SIMD.

#define EMB   128
#define HID   256
#define NCLS  32
#define DIM   256   // feature width everywhere (2*EMB == HID == 256)

typedef __attribute__((ext_vector_type(8))) short short8v;   // 8 bf16 = 4 VGPR (MFMA A/B frag)
typedef __attribute__((ext_vector_type(4))) float float4v;   // MFMA C/D frag

__device__ __forceinline__ unsigned short f2bf(float f) {    // RNE fp32->bf16 (normals)
    unsigned int u = __float_as_uint(f);
    unsigned int r = u + 0x7FFFu + ((u >> 16) & 1u);
    return (unsigned short)(r >> 16);
}
__device__ __forceinline__ float bf2f(unsigned short s) {
    return __uint_as_float(((unsigned int)s) << 16);
}

// ---------------------------------------------------------------- weight precompute
// Bq[k][o] = k<256 ? wl[o,k] : wr[o,k-256], bf16 hi/lo, fragment-native:
// idx = ((k>>3)*256 + o)*8 + (k&7). Both layers in one launch.
__global__ void build_bq2(const float* __restrict__ w1l, const float* __restrict__ w1r,
                          const float* __restrict__ w2l, const float* __restrict__ w2r,
                          unsigned short* __restrict__ b1hi, unsigned short* __restrict__ b1lo,
                          unsigned short* __restrict__ b2hi, unsigned short* __restrict__ b2lo) {
    int tid = blockIdx.x * 256 + threadIdx.x;   // 2*512*256 threads
    int which = tid >> 17;
    int r = tid & 0x1FFFF;
    int k = r >> 8, o = r & 255;
    const float* wl = which ? w2l : w1l;
    const float* wr = which ? w2r : w1r;
    float v = (k < 256) ? wl[o * 256 + k] : wr[o * 256 + (k - 256)];
    unsigned short h = f2bf(v);
    unsigned short l = f2bf(v - bf2f(h));
    int idx = (((k >> 3) * 256) + o) * 8 + (k & 7);
    (which ? b2hi : b1hi)[idx] = h;
    (which ? b2lo : b1lo)[idx] = l;
}

// h0: row-major bf16 (for gathers) + fragment-native bf16 (for GEMM phase 2)
__global__ void embed_bf16(const int* __restrict__ x,
                           const float* __restrict__ se, const float* __restrict__ ce,
                           unsigned short* __restrict__ hb, unsigned short* __restrict__ hf,
                           int n_nodes) {
    int tid = blockIdx.x * 256 + threadIdx.x;   // n_nodes*32
    if (tid >= n_nodes * 32) return;
    int n = tid >> 5, c = tid & 31;             // c = k-octet index (8 elems)
    const float* src = (c < 16) ? (se + (size_t)x[n * 2] * EMB + c * 8)
                                : (ce + (size_t)x[n * 2 + 1] * EMB + (c - 16) * 8);
    float4 v0 = *(const float4*)src;
    float4 v1 = *(const float4*)(src + 4);
    ushort4 o0 = make_ushort4(f2bf(v0.x), f2bf(v0.y), f2bf(v0.z), f2bf(v0.w));
    ushort4 o1 = make_ushort4(f2bf(v1.x), f2bf(v1.y), f2bf(v1.z), f2bf(v1.w));
    *(ushort4*)(hb + (size_t)tid * 8)     = o0;
    *(ushort4*)(hb + (size_t)tid * 8 + 4) = o1;
    size_t fo = ((size_t)(n >> 4) * 32 + c) * 128 + (n & 15) * 8;
    *(ushort4*)(hf + fo)     = o0;
    *(ushort4*)(hf + fo + 4) = o1;
}

// ---------------------------------------------------------------- CSR build

__global__ void count_deg(const int* __restrict__ dst, int* __restrict__ deg, int E) {
    int e = blockIdx.x * 256 + threadIdx.x;
    if (e < E) atomicAdd(&deg[dst[e]], 1);
}

__global__ void scan_block(const int* __restrict__ deg, int* __restrict__ rowptr,
                           int* __restrict__ bsums, int n) {
    __shared__ int s[256];
    int t = threadIdx.x;
    int i = blockIdx.x * 256 + t;
    int v = (i < n) ? deg[i] : 0;
    s[t] = v; __syncthreads();
    for (int off = 1; off < 256; off <<= 1) {
        int x = (t >= off) ? s[t - off] : 0;
        __syncthreads(); s[t] += x; __syncthreads();
    }
    if (i < n) rowptr[i] = s[t] - v;
    if (t == 255) bsums[blockIdx.x] = s[255];
}

__global__ void scan_sums(int* __restrict__ bsums, int nb, int* __restrict__ rowptr,
                          int n, int E) {
    __shared__ int s[256];
    int t = threadIdx.x;
    int v = (t < nb) ? bsums[t] : 0;
    s[t] = v; __syncthreads();
    for (int off = 1; off < 256; off <<= 1) {
        int x = (t >= off) ? s[t - off] : 0;
        __syncthreads(); s[t] += x; __syncthreads();
    }
    if (t < nb) bsums[t] = s[t] - v;
    if (t == 0) rowptr[n] = E;
}

__global__ void scan_add(int* __restrict__ rowptr, const int* __restrict__ bsums, int n) {
    int i = blockIdx.x * 256 + threadIdx.x;
    if (i < n) rowptr[i] += bsums[i >> 8];
}

__global__ void fill_csr(const int* __restrict__ src, const int* __restrict__ dst,
                         const int* __restrict__ rowptr, int* __restrict__ cursor,
                         int* __restrict__ csr, int E) {
    int e = blockIdx.x * 256 + threadIdx.x;
    if (e >= E) return;
    int d = dst[e];
    int pos = rowptr[d] + atomicAdd(&cursor[d], 1);
    csr[pos] = src[e];
}

// ---------------------------------------------------------------- mean aggregation
// one wave per node; lane l owns k = 4l..4l+3 (8B gather per lane); unroll-4.
// Output: bf16 hi/lo planes in FRAGMENT-NATIVE layout.
__global__ void aggregate_bf16(const unsigned short* __restrict__ hb,
                               const int* __restrict__ rowptr, const int* __restrict__ csr,
                               unsigned short* __restrict__ ahiF, unsigned short* __restrict__ aloF,
                               int n_nodes) {
    int wid = (blockIdx.x * 256 + threadIdx.x) >> 6;
    int lane = threadIdx.x & 63;
    if (wid >= n_nodes) return;
    int beg = rowptr[wid], end = rowptr[wid + 1];
    float a0 = 0.f, a1 = 0.f, a2 = 0.f, a3 = 0.f;
    int k = beg;
    for (; k + 3 < end; k += 4) {
        int s0 = csr[k], s1 = csr[k + 1], s2 = csr[k + 2], s3 = csr[k + 3];
        ushort4 u0 = *(const ushort4*)(hb + (size_t)s0 * DIM + lane * 4);
        ushort4 u1 = *(const ushort4*)(hb + (size_t)s1 * DIM + lane * 4);
        ushort4 u2 = *(const ushort4*)(hb + (size_t)s2 * DIM + lane * 4);
        ushort4 u3 = *(const ushort4*)(hb + (size_t)s3 * DIM + lane * 4);
        a0 += bf2f(u0.x) + bf2f(u1.x) + bf2f(u2.x) + bf2f(u3.x);
        a1 += bf2f(u0.y) + bf2f(u1.y) + bf2f(u2.y) + bf2f(u3.y);
        a2 += bf2f(u0.z) + bf2f(u1.z) + bf2f(u2.z) + bf2f(u3.z);
        a3 += bf2f(u0.w) + bf2f(u1.w) + bf2f(u2.w) + bf2f(u3.w);
    }
    for (; k < end; ++k) {
        ushort4 u = *(const ushort4*)(hb + (size_t)csr[k] * DIM + lane * 4);
        a0 += bf2f(u.x); a1 += bf2f(u.y); a2 += bf2f(u.z); a3 += bf2f(u.w);
    }
    int d = end - beg;
    float inv = 1.0f / (float)(d > 1 ? d : 1);
    float v[4] = {a0 * inv, a1 * inv, a2 * inv, a3 * inv};
    unsigned short hs[4], ls[4];
#pragma unroll
    for (int i = 0; i < 4; ++i) {
        hs[i] = f2bf(v[i]);
        ls[i] = f2bf(v[i] - bf2f(hs[i]));
    }
    size_t base = ((size_t)(wid >> 4) * 32 + (lane >> 1)) * 128 + (wid & 15) * 8 + (lane & 1) * 4;
    *(ushort4*)(ahiF + base) = make_ushort4(hs[0], hs[1], hs[2], hs[3]);
    *(ushort4*)(aloF + base) = make_ushort4(ls[0], ls[1], ls[2], ls[3]);
}

// ---------------------------------------------------------------- MFMA SAGE GEMM v3
// Hout[m,n] = relu( sum_k Agg[m,k]*Wl[n,k] + Hin[m,k]*Wr[n,k] + bias[n] )
// BM=64, BN=256 (A read ONCE per block). 8 waves (512 thr), wave tile 64x32.
// Block's Ahi/Alo (64KB frag-native, contiguous) staged to LDS once ->
// K-loop phase 1 reads A via conflict-free ds_read_b128. Phase 2 Hf from
// global (uniform across waves -> L1). B frag-native from L2.
__global__ void __launch_bounds__(512, 4)
gemm_mfma(const unsigned short* __restrict__ Ahi, const unsigned short* __restrict__ Alo,
          const unsigned short* __restrict__ Hf,
          const unsigned short* __restrict__ Bhi, const unsigned short* __restrict__ Blo,
          const float* __restrict__ bias,
          float* __restrict__ Houtf, unsigned short* __restrict__ Houtb,
          unsigned short* __restrict__ Hfrag, int M) {
    __shared__ __align__(16) unsigned short lds_a[32768];   // [hi:16384][lo:16384] ushorts

    const int t = threadIdx.x;
    const int w = t >> 6, lane = t & 63;
    const int lrow = lane & 15, koct = lane >> 4;
    const int m0 = blockIdx.x * 64;               // block rows (shared by all waves)
    const int nw = w * 32;                        // wave col base (8 waves x 32)
    const int mbmax = (M >> 4) - 1;

    // ---- stage Ahi/Alo (64KB) into LDS: 8 x 16B per thread, coalesced ----
#pragma unroll
    for (int i = 0; i < 8; ++i) {                 // i<4: hi row-block i; i>=4: lo row-block i-4
        int rb = i & 3;
        int mb = (m0 >> 4) + rb;
        if (mb > mbmax) mb = mbmax;
        const unsigned short* srcp = ((i < 4) ? Ahi : Alo) + (size_t)mb * 4096 + t * 8;
        *(short8v*)&lds_a[((i < 4) ? 0 : 16384) + rb * 4096 + t * 8] =
            *(const short8v*)srcp;
    }

    // phase-2 global A bases (Hf), clamped
    size_t abase[4];
#pragma unroll
    for (int mt = 0; mt < 4; ++mt) {
        int mb = (m0 >> 4) + mt;
        if (mb > mbmax) mb = mbmax;
        abase[mt] = (size_t)mb * 32 * 128 + lrow * 8;
    }
    const int col0 = nw + lrow;

    float4v acc[4][2];
#pragma unroll
    for (int i = 0; i < 4; ++i)
#pragma unroll
        for (int j = 0; j < 2; ++j) acc[i][j] = (float4v){0.f, 0.f, 0.f, 0.f};

    __syncthreads();                              // staging complete

    // ---- phase 1: K = 0..255 (Agg hi/lo from LDS, 3 MFMAs per frag pair) ----
#pragma unroll 2
    for (int kt = 0; kt < 8; ++kt) {
        const int kof = (kt * 4 + koct) * 128 + lrow * 8;
        const int kg = kt * 4 + koct;
        short8v ah[4], al[4], bh[2], bl[2];
#pragma unroll
        for (int mt = 0; mt < 4; ++mt) {
            ah[mt] = *(const short8v*)&lds_a[mt * 4096 + kof];
            al[mt] = *(const short8v*)&lds_a[16384 + mt * 4096 + kof];
        }
#pragma unroll
        for (int nt = 0; nt < 2; ++nt) {
            size_t bofs = ((size_t)kg * 256 + col0 + nt * 16) * 8;
            bh[nt] = *(const short8v*)(Bhi + bofs);
            bl[nt] = *(const short8v*)(Blo + bofs);
        }
#pragma unroll
        for (int mt = 0; mt < 4; ++mt)
#pragma unroll
            for (int nt = 0; nt < 2; ++nt) {
                acc[mt][nt] = __builtin_amdgcn_mfma_f32_16x16x32_bf16(ah[mt], bh[nt], acc[mt][nt], 0, 0, 0);
                acc[mt][nt] = __builtin_amdgcn_mfma_f32_16x16x32_bf16(ah[mt], bl[nt], acc[mt][nt], 0, 0, 0);
                acc[mt][nt] = __builtin_amdgcn_mfma_f32_16x16x32_bf16(al[mt], bh[nt], acc[mt][nt], 0, 0, 0);
            }
    }

    // ---- phase 2: K = 256..511 (Hin bf16 exact from global, 2 MFMAs) ----
#pragma unroll 2
    for (int kt = 0; kt < 8; ++kt) {
        const size_t kof = (size_t)(kt * 4 + koct) * 128;
        const int kg = (kt + 8) * 4 + koct;
        short8v ah[4], bh[2], bl[2];
#pragma unroll
        for (int mt = 0; mt < 4; ++mt)
            ah[mt] = *(const short8v*)(Hf + abase[mt] + kof);
#pragma unroll
        for (int nt = 0; nt < 2; ++nt) {
            size_t bofs = ((size_t)kg * 256 + col0 + nt * 16) * 8;
            bh[nt] = *(const short8v*)(Bhi + bofs);
            bl[nt] = *(const short8v*)(Blo + bofs);
        }
#pragma unroll
        for (int mt = 0; mt < 4; ++mt)
#pragma unroll
            for (int nt = 0; nt < 2; ++nt) {
                acc[mt][nt] = __builtin_amdgcn_mfma_f32_16x16x32_bf16(ah[mt], bh[nt], acc[mt][nt], 0, 0, 0);
                acc[mt][nt] = __builtin_amdgcn_mfma_f32_16x16x32_bf16(ah[mt], bl[nt], acc[mt][nt], 0, 0, 0);
            }
    }

    // ---- epilogue: bias + relu; C/D map col=lane&15, row=(lane>>4)*4+reg ----
    float bv[2];
#pragma unroll
    for (int nt = 0; nt < 2; ++nt) bv[nt] = bias[nw + nt * 16 + lrow];

#pragma unroll
    for (int mt = 0; mt < 4; ++mt) {
#pragma unroll
        for (int r = 0; r < 4; ++r) {
            int grow = m0 + mt * 16 + koct * 4 + r;
            if (grow >= M) continue;
            size_t fbase = ((size_t)(grow >> 4) * 32) * 128 + (grow & 15) * 8;
#pragma unroll
            for (int nt = 0; nt < 2; ++nt) {
                float vv = fmaxf(acc[mt][nt][r] + bv[nt], 0.f);
                int col = nw + nt * 16 + lrow;
                if (Houtf) Houtf[(size_t)grow * DIM + col] = vv;
                if (Houtb) Houtb[(size_t)grow * DIM + col] = f2bf(vv);
                if (Hfrag) Hfrag[fbase + (size_t)(col >> 3) * 128 + (col & 7)] = f2bf(vv);
            }
        }
    }
}

// ---------------------------------------------------------------- pooling + head

__global__ void pool_kernel(const float* __restrict__ h, const int* __restrict__ batch,
                            float* __restrict__ hg, int n_nodes) {
    int g = blockIdx.x;
    int t = threadIdx.x;
    int lo = 0, hi = n_nodes;
    while (lo < hi) { int mid = (lo + hi) >> 1; if (batch[mid] < g) lo = mid + 1; else hi = mid; }
    int start = lo;
    hi = n_nodes;
    while (lo < hi) { int mid = (lo + hi) >> 1; if (batch[mid] < g + 1) lo = mid + 1; else hi = mid; }
    int end = lo;
    float acc = 0.f;
    for (int n = start; n < end; ++n) acc += h[(size_t)n * DIM + t];
    int c = end - start;
    hg[g * DIM + t] = acc / (float)(c > 1 ? c : 1);
}

__global__ void head_kernel(const float* __restrict__ hg, const float* __restrict__ wc,
                            const float* __restrict__ bc, float* __restrict__ out, int total) {
    int tid = blockIdx.x * 256 + threadIdx.x;
    if (tid >= total) return;
    int g = tid >> 5, c = tid & 31;
    const float* hr = hg + (size_t)g * DIM;
    const float* wr = wc + (size_t)c * DIM;
    float acc = bc[c];
    for (int k = 0; k < DIM; ++k) acc = fmaf(hr[k], wr[k], acc);
    out[tid] = acc;
}

// ---------------------------------------------------------------- launch

extern "C" void kernel_launch(void* const* d_in, const int* in_sizes, int n_in,
                              void* d_out, int out_size, void* d_ws, size_t ws_size,
                              hipStream_t stream) {
    const int* x      = (const int*)d_in[0];
    const int* ei     = (const int*)d_in[1];
    const int* batch  = (const int*)d_in[2];
    const float* se   = (const float*)d_in[3];
    const float* ce   = (const float*)d_in[4];
    const float* w1l  = (const float*)d_in[5];
    const float* b1l  = (const float*)d_in[6];
    const float* w1r  = (const float*)d_in[7];
    const float* w2l  = (const float*)d_in[8];
    const float* b2l  = (const float*)d_in[9];
    const float* w2r  = (const float*)d_in[10];
    const float* wc   = (const float*)d_in[11];
    const float* bc   = (const float*)d_in[12];
    float* out = (float*)d_out;

    const int N = in_sizes[0] / 2;
    const int E = in_sizes[1] / 2;
    const int G = out_size / NCLS;
    const int* src = ei;
    const int* dst = ei + E;

    // workspace carve-up
    float* h2 = (float*)d_ws;                               // N*256 f32
    unsigned short* agghiF = (unsigned short*)(h2 + (size_t)N * DIM); // frag-native planes
    unsigned short* aggloF = agghiF + (size_t)N * DIM;
    unsigned short* h0b    = aggloF + (size_t)N * DIM;      // row-major (gather)
    unsigned short* h0f    = h0b + (size_t)N * DIM;         // frag-native
    unsigned short* h1b    = h0f + (size_t)N * DIM;         // row-major (gather)
    unsigned short* h1f    = h1b + (size_t)N * DIM;         // frag-native
    unsigned short* B1hi   = h1f + (size_t)N * DIM;         // 512*256 each
    unsigned short* B1lo   = B1hi + 131072;
    unsigned short* B2hi   = B1lo + 131072;
    unsigned short* B2lo   = B2hi + 131072;
    float* hg  = (float*)(B2lo + 131072);                   // G*256
    int* deg    = (int*)(hg + (size_t)G * DIM);             // N
    int* rowptr = deg + N;                                  // N+1
    int* cursor = rowptr + (N + 1);                         // N
    int* csr    = cursor + N;                               // E
    int* bsums  = csr + E;                                  // <=256

    hipMemsetAsync(deg, 0, (size_t)(3 * N + 1) * sizeof(int), stream);

    embed_bf16<<<(N * 32 + 255) / 256, 256, 0, stream>>>(x, se, ce, h0b, h0f, N);

    int eblocks = (E + 255) / 256;
    count_deg<<<eblocks, 256, 0, stream>>>(dst, deg, E);
    int sblocks = (N + 255) / 256;
    scan_block<<<sblocks, 256, 0, stream>>>(deg, rowptr, bsums, N);
    scan_sums<<<1, 256, 0, stream>>>(bsums, sblocks, rowptr, N, E);
    scan_add<<<sblocks, 256, 0, stream>>>(rowptr, bsums, N);
    fill_csr<<<eblocks, 256, 0, stream>>>(src, dst, rowptr, cursor, csr, E);

    build_bq2<<<1024, 256, 0, stream>>>(w1l, w1r, w2l, w2r, B1hi, B1lo, B2hi, B2lo);

    int gblocks = (N + 63) / 64;                            // 782 (BM=64, BN=256)
    int ablocks = (N * 64 + 255) / 256;

    // layer 1: h0b -> agg(frag hi/lo) -> h1b (row-major) + h1f (frag-native)
    aggregate_bf16<<<ablocks, 256, 0, stream>>>(h0b, rowptr, csr, agghiF, aggloF, N);
    gemm_mfma<<<gblocks, 512, 0, stream>>>(agghiF, aggloF, h0f, B1hi, B1lo, b1l,
                                           nullptr, h1b, h1f, N);

    // layer 2: h1b -> agg(frag hi/lo) -> h2 (fp32 row-major for pooling)
    aggregate_bf16<<<ablocks, 256, 0, stream>>>(h1b, rowptr, csr, agghiF, aggloF, N);
    gemm_mfma<<<gblocks, 512, 0, stream>>>(agghiF, aggloF, h1f, B2hi, B2lo, b2l,
                                           h2, nullptr, nullptr, N);

    pool_kernel<<<G, 256, 0, stream>>>(h2, batch, hg, N);
    head_kernel<<<(G * NCLS + 255) / 256, 256, 0, stream>>>(hg, wc, bc, out, G * NCLS);
}